// Round 15
// baseline (5664.621 us; speedup 1.0000x reference)
//
#include <hip/hip_runtime.h>
#include <hip/hip_bf16.h>
#include <math.h>

// ---------------- problem constants ----------------
#define T_STEPS 256
#define BATCH   16
#define FDIM    256
#define NTOT    4096
#define NNZ     512
#define NWG     64

#define MAXK    20          // weight blocks in VGPRs (guarded) + s col-blocks staged in LDS
#define STG_SWEEPS 10       // MAXK*2048 / (256*16)
#define DEPTH   8           // s exchange ring buffers

// workspace layout (bytes) — identical footprint to round 5/12 (proven to fit)
#define FLAGS_OFF 0                          // 64 flags, 64B apart (single-writer lines)
#define SBF_OFF   4096
#define SBUF_BYTES (64*BATCH*64*2)           // 131072 per ring buffer (block-major)
#define WFRAG_OFF (4096 + DEPTH*SBUF_BYTES)  // 1052672; + 4 MB fragments

typedef float f32x4 __attribute__((ext_vector_type(4)));
typedef short bf16x8 __attribute__((ext_vector_type(8)));

__device__ __forceinline__ unsigned short f2bf(float x) {
  unsigned u = __float_as_uint(x);
  u += 0x7fffu + ((u >> 16) & 1u);
  return (unsigned short)(u >> 16);
}

// ---- device-coherence-point ops (sc0 sc1): proven correct cross-WG (R2/R5/R12) ----
__device__ __forceinline__ bf16x8 sc_load16(const void* p) {
  bf16x8 r;
  asm volatile("global_load_dwordx4 %0, %1, off sc0 sc1"
               : "=&v"(r) : "v"(p) : "memory");
  return r;
}
__device__ __forceinline__ bf16x8 sc_load16_wait(const void* p) {
  bf16x8 r;
  asm volatile("global_load_dwordx4 %0, %1, off sc0 sc1\n\ts_waitcnt vmcnt(0)"
               : "=&v"(r) : "v"(p) : "memory");
  return r;
}
__device__ __forceinline__ void sc_store_short(void* p, unsigned v) {
  asm volatile("global_store_short %0, %1, off sc0 sc1"
               :: "v"(p), "v"(v) : "memory");
}
__device__ __forceinline__ void sc_store_u32(void* p, unsigned v) {
  asm volatile("global_store_dword %0, %1, off sc0 sc1"
               :: "v"(p), "v"(v) : "memory");
}
// publish store: atomic swap (no return) — executes & ACKs at the coherence
// point instead of write-through-to-HBM ACK; sc1 keeps it device-coherent.
__device__ __forceinline__ void sc_atomic_swap(void* p, unsigned v) {
  asm volatile("global_atomic_swap %0, %1, off sc1"
               :: "v"(p), "v"(v) : "memory");
}

// ---------------- init: zero flag region (1024 dwords) at the coherence point ----
__global__ void k_init(unsigned* __restrict__ flags) {
  for (int j = threadIdx.x; j < 1024; j += 256) sc_store_u32(flags + j, 0u);
}

// ---------------- drive GEMM: drive[m][n] = gain[n]*sum_f ext[m][f]*win[n][f] + bias[n]
__global__ __launch_bounds__(256) void k_gemm(const float* __restrict__ ext,
                                              const float* __restrict__ win,
                                              const float* __restrict__ gain,
                                              const float* __restrict__ bias,
                                              float* __restrict__ drive) {
  __shared__ float As[64][68];
  __shared__ float WsT[64][68];
  const int tid = threadIdx.x;
  const int m0 = blockIdx.y << 6;
  const int n0 = blockIdx.x << 6;
  const int tx = tid & 15, ty = tid >> 4;
  float acc[4][4] = {};
  for (int kc = 0; kc < FDIM; kc += 64) {
    __syncthreads();
#pragma unroll
    for (int rep = 0; rep < 4; ++rep) {
      int idx = tid + rep * 256;
      int row = idx >> 4;
      int c4 = (idx & 15) << 2;
      float4 av = *(const float4*)&ext[(size_t)(m0 + row) * FDIM + kc + c4];
      *(float4*)&As[row][c4] = av;
      float4 wv4 = *(const float4*)&win[(size_t)(n0 + row) * FDIM + kc + c4];
      WsT[c4 + 0][row] = wv4.x; WsT[c4 + 1][row] = wv4.y;
      WsT[c4 + 2][row] = wv4.z; WsT[c4 + 3][row] = wv4.w;
    }
    __syncthreads();
#pragma unroll 4
    for (int k = 0; k < 64; ++k) {
      float a_[4], w_[4];
#pragma unroll
      for (int i = 0; i < 4; ++i) a_[i] = As[ty * 4 + i][k];
#pragma unroll
      for (int j = 0; j < 4; ++j) w_[j] = WsT[k][tx * 4 + j];
#pragma unroll
      for (int i = 0; i < 4; ++i)
#pragma unroll
        for (int j = 0; j < 4; ++j) acc[i][j] = fmaf(a_[i], w_[j], acc[i][j]);
    }
  }
#pragma unroll
  for (int i = 0; i < 4; ++i) {
    int m = m0 + ty * 4 + i;
#pragma unroll
    for (int j = 0; j < 4; ++j) {
      int n = n0 + tx * 4 + j;
      drive[(size_t)m * NTOT + n] = gain[n] * acc[i][j] + bias[n];
    }
  }
}

// ---------------- weight prep: fragment-linear bf16 (B-operand) ----------------
__global__ __launch_bounds__(256) void k_wprep(const float* __restrict__ wv,
                                               unsigned short* __restrict__ wfrag) {
  const int sl = blockIdx.x;
  const int kk2 = blockIdx.y;
  const int tid = threadIdx.x;
  const int l = tid & 63, wt = tid >> 6;
  const int c = l & 15, g = l >> 4;
  const int i = wt * 16 + c;
  __align__(16) unsigned short tmp[8];
#pragma unroll
  for (int e = 0; e < 8; ++e) {
    int j = kk2 * 32 + g * 8 + e;
    tmp[e] = f2bf(wv[((size_t)sl * 64 + i) * 64 + j]);
  }
  size_t off = (((size_t)(sl * 2 + kk2) * 4 + wt) * 64 + l) * 8;
  *(uint4*)(wfrag + off) = *(const uint4*)tmp;
}

// ---- persistent recurrent kernel: R12 + atomic-pair publish (CP-ACK drain) ----
__global__ __launch_bounds__(256, 1) void k_persist(const float* __restrict__ s0,
                                                    const int* __restrict__ rows_g,
                                                    const int* __restrict__ cols_g,
                                                    const unsigned short* __restrict__ wfrag,
                                                    char* __restrict__ sbuf,
                                                    float* __restrict__ out,
                                                    unsigned* __restrict__ flags) {
  __shared__ char sstage[MAXK * 2048];   // XOR-swizzled staged s col-blocks
  __shared__ int sh_cols[64];
  __shared__ int sh_lt, sh_eq;
  __shared__ unsigned m_pl, m_ph, m_cl, m_ch;

  const int r = blockIdx.x;
  const int tid = threadIdx.x;
  const int l = tid & 63, wt = tid >> 6;
  const int c = l & 15, g = l >> 4;
  const int n_own = r * 64 + wt * 16 + c;
  const float d_f = 0.81873077f;   // exp(-0.2f)
  const float omd = 1.0f - d_f;

  // ---- scan rows/cols: nnz range + producer/consumer masks ----
  if (tid == 0) { sh_lt = 0; sh_eq = 0; m_pl = 0; m_ph = 0; m_cl = 0; m_ch = 0; }
  __syncthreads();
  {
    int lt = 0, eq = 0;
    for (int k = tid; k < NNZ; k += 256) {
      int rv = rows_g[k], cv = cols_g[k];
      lt += (rv < r); eq += (rv == r);
      if (rv == r) { if (cv < 32) atomicOr(&m_pl, 1u << cv); else atomicOr(&m_ph, 1u << (cv - 32)); }
      if (cv == r) { if (rv < 32) atomicOr(&m_cl, 1u << rv); else atomicOr(&m_ch, 1u << (rv - 32)); }
    }
    atomicAdd(&sh_lt, lt); atomicAdd(&sh_eq, eq);
  }
  __syncthreads();
  const int start = sh_lt;
  const int cnt = min(sh_eq, 64);
  if (tid < cnt) sh_cols[tid] = cols_g[start + tid];
  __syncthreads();
  const unsigned long long pmask = ((unsigned long long)m_ph << 32) | m_pl;
  const unsigned long long cmask = ((unsigned long long)m_ch << 32) | m_cl;

  // ---- weights -> registers (guarded loads; proven layout from round 5/12) ----
  const char* wfb = (const char*)wfrag;
  bf16x8 wb0[MAXK], wb1[MAXK];
#pragma unroll
  for (int k = 0; k < MAXK; ++k) {
    if (k < cnt) {
      const char* bb = wfb + (size_t)(start + k) * 8192 + (size_t)(wt * 64 + l) * 16;
      wb0[k] = *(const bf16x8*)(bb);
      wb1[k] = *(const bf16x8*)(bb + 4096);
    }
  }
  const int cnt2 = min(cnt, MAXK);

  // ---- init state; publish s^(0) to ring slot 0 ----
  float sreg[4];
#pragma unroll
  for (int q = 0; q < 4; ++q) sreg[q] = s0[(size_t)(g * 4 + q) * NTOT + n_own];
  {
    char* me = sbuf + (size_t)r * 2048;
#pragma unroll
    for (int q = 0; q < 4; ++q)
      sc_store_short(me + (g * 4 + q) * 128 + (wt * 16 + c) * 2, (unsigned)f2bf(sreg[q]));
  }
  float drv[4];
#pragma unroll
  for (int q = 0; q < 4; ++q) drv[q] = out[(size_t)(g * 4 + q) * NTOT + n_own];

  asm volatile("s_waitcnt vmcnt(0)" ::: "memory");
  __syncthreads();
  if (tid == 0) sc_store_u32(&flags[(size_t)r * 16], 1u);

  const int raw0 = (c * 128 + g * 16) ^ ((c & 7) << 4);
  const int raw1 = (c * 128 + 64 + g * 16) ^ ((c & 7) << 4);
  const int nbytes = cnt2 * 2048;
  int budget = 1 << 20;   // global fast-fail budget: bug -> finish fast, never hang

  for (int t = 0; t < T_STEPS; ++t) {
    for (int ss = 0; ss < 5; ++ss) {
      const int i = t * 5 + ss + 1;

      // ---- poll (wave 0, participating lanes only): producers >= i; consumers >= i-6
      if (tid < 64) {
        const int nc = i - (DEPTH - 2);
        const bool par = (((pmask | cmask) >> l) & 1ull) != 0;
        const unsigned* fp = flags + (size_t)l * 16;   // one 64B line per WG
        for (;;) {
          unsigned f = 0x7FFFFFFFu;
          if (par)
            asm volatile("global_load_dword %0, %1, off sc0 sc1\n\ts_waitcnt vmcnt(0)"
                         : "=&v"(f) : "v"(fp) : "memory");
          unsigned long long bp = __ballot((int)f >= i);
          unsigned long long bc = __ballot((int)f >= nc);
          if (((bp & pmask) == pmask) && ((bc & cmask) == cmask)) break;
          if (--budget < 0) break;
          __builtin_amdgcn_s_sleep(1);
        }
      }
      __syncthreads();

      // ---- stage s col-blocks into swizzled LDS (pipelined coherent loads) ----
      const char* sb_prev = sbuf + (size_t)((i - 1) & (DEPTH - 1)) * SBUF_BYTES;
      bf16x8 stg[STG_SWEEPS];
#pragma unroll
      for (int sw = 0; sw < STG_SWEEPS; ++sw) {
        int off = tid * 16 + sw * 4096;
        if (off < nbytes) {
          int blk = off >> 11;
          int r2 = off & 2047;
          stg[sw] = sc_load16(sb_prev + (size_t)sh_cols[blk] * 2048 + r2);
        }
      }
      asm volatile("s_waitcnt vmcnt(0)" ::: "memory");
      __builtin_amdgcn_sched_barrier(0);
#pragma unroll
      for (int sw = 0; sw < STG_SWEEPS; ++sw) {
        int off = tid * 16 + sw * 4096;
        if (off < nbytes) {
          int blk = off >> 11;
          int r2 = off & 2047;
          int b = r2 >> 7;
          int jl = r2 & 127;
          *(bf16x8*)(sstage + blk * 2048 + ((b * 128 + jl) ^ ((b & 7) << 4))) = stg[sw];
        }
      }
      __syncthreads();

      // ---- block-sparse matvec: VGPR weights x LDS s-fragments ----
      f32x4 acc = {0.f, 0.f, 0.f, 0.f};
#pragma unroll
      for (int k = 0; k < MAXK; ++k) {
        if (k < cnt2) {
          const char* ab = sstage + k * 2048;
          bf16x8 a0 = *(const bf16x8*)(ab + raw0);
          bf16x8 a1 = *(const bf16x8*)(ab + raw1);
          acc = __builtin_amdgcn_mfma_f32_16x16x32_bf16(a0, wb0[k], acc, 0, 0, 0);
          acc = __builtin_amdgcn_mfma_f32_16x16x32_bf16(a1, wb1[k], acc, 0, 0, 0);
        }
      }
      for (int k = MAXK; k < cnt; ++k) {   // rare overflow: direct coherent reads
        const char* bb = wfb + (size_t)(start + k) * 8192 + (size_t)(wt * 64 + l) * 16;
        bf16x8 b0 = *(const bf16x8*)(bb);
        bf16x8 b1 = *(const bf16x8*)(bb + 4096);
        const char* ab = sb_prev + (size_t)sh_cols[k] * 2048 + c * 128 + g * 16;
        bf16x8 a0 = sc_load16_wait(ab);
        bf16x8 a1 = sc_load16_wait(ab + 64);
        acc = __builtin_amdgcn_mfma_f32_16x16x32_bf16(a0, b0, acc, 0, 0, 0);
        acc = __builtin_amdgcn_mfma_f32_16x16x32_bf16(a1, b1, acc, 0, 0, 0);
      }

      // ---- state update; publish s^(i) via ATOMIC pair stores (CP-ACK, not HBM-ACK).
      //      Lanes l and l^1 hold neurons n and n^1 (same batches): shfl_xor packs
      //      the dword; even lanes store. Byte layout identical to R12. ----
      char* me = sbuf + (size_t)(i & (DEPTH - 1)) * SBUF_BYTES + (size_t)r * 2048;
#pragma unroll
      for (int q = 0; q < 4; ++q) {
        float pre = acc[q] + drv[q];
        sreg[q] = d_f * sreg[q] + omd * tanhf(pre);
        unsigned own = (unsigned)f2bf(sreg[q]);
        unsigned part = (unsigned)__shfl_xor((int)own, 1, 64);
        if (!(l & 1)) {
          unsigned pk = own | (part << 16);
          sc_atomic_swap(me + (g * 4 + q) * 128 + (wt * 16 + c) * 2, pk);
        }
      }
      asm volatile("s_waitcnt vmcnt(0)" ::: "memory");
      asm volatile("s_barrier" ::: "memory");
      if (tid == 0) sc_store_u32(&flags[(size_t)r * 16], (unsigned)(i + 1));

      if (ss == 4) {
        // traj[t] = s (plain cached stores, drained lazily by later vmcnts)
#pragma unroll
        for (int q = 0; q < 4; ++q)
          out[((size_t)t * BATCH + (g * 4 + q)) * NTOT + n_own] = sreg[q];
        if (t + 1 < T_STEPS) {
#pragma unroll
          for (int q = 0; q < 4; ++q)
            drv[q] = out[((size_t)(t + 1) * BATCH + (g * 4 + q)) * NTOT + n_own];
        }
      }
    }
  }
}

// ---------------- launcher ----------------
extern "C" void kernel_launch(void* const* d_in, const int* in_sizes, int n_in,
                              void* d_out, int out_size, void* d_ws, size_t ws_size,
                              hipStream_t stream) {
  const float* ext  = (const float*)d_in[0];
  const float* win  = (const float*)d_in[1];
  const float* gain = (const float*)d_in[2];
  const float* bias = (const float*)d_in[3];
  const float* wv   = (const float*)d_in[4];
  const float* s0   = (const float*)d_in[5];
  const int* rows = (const int*)d_in[8];
  const int* cols = (const int*)d_in[9];
  float* out = (float*)d_out;

  char* ws = (char*)d_ws;
  unsigned* flags = (unsigned*)(ws + FLAGS_OFF);
  char* sbuf = ws + SBF_OFF;
  unsigned short* wfrag = (unsigned short*)(ws + WFRAG_OFF);

  k_init<<<1, 256, 0, stream>>>(flags);
  k_gemm<<<dim3(64, 64), 256, 0, stream>>>(ext, win, gain, bias, out);
  k_wprep<<<dim3(512, 2), 256, 0, stream>>>(wv, wfrag);
  k_persist<<<NWG, 256, 0, stream>>>(s0, rows, cols, wfrag, sbuf, out, flags);
}

// Round 16
// 5448.849 us; speedup vs baseline: 1.0396x; 1.0396x over previous
//
#include <hip/hip_runtime.h>
#include <hip/hip_bf16.h>
#include <math.h>

// ---------------- problem constants ----------------
#define T_STEPS 256
#define BATCH   16
#define FDIM    256
#define NTOT    4096
#define NNZ     512
#define NWG     64

#define MAXK    20          // weight blocks in VGPRs (guarded) + s col-blocks staged in LDS
#define STG_SWEEPS 10       // MAXK*2048 / (256*16)
#define DEPTH   8           // s exchange ring buffers

// workspace layout (bytes) — identical footprint to round 5/12 (proven to fit)
#define FLAGS_OFF 0                          // 64 flags, 64B apart (single-writer lines)
#define SBF_OFF   4096
#define SBUF_BYTES (64*BATCH*64*2)           // 131072 per ring buffer (block-major)
#define WFRAG_OFF (4096 + DEPTH*SBUF_BYTES)  // 1052672; + 4 MB fragments

typedef float f32x4 __attribute__((ext_vector_type(4)));
typedef short bf16x8 __attribute__((ext_vector_type(8)));

__device__ __forceinline__ unsigned short f2bf(float x) {
  unsigned u = __float_as_uint(x);
  u += 0x7fffu + ((u >> 16) & 1u);
  return (unsigned short)(u >> 16);
}

// ---- device-coherence-point ops (sc0 sc1): proven correct cross-WG (R2/R5/R12) ----
__device__ __forceinline__ bf16x8 sc_load16(const void* p) {
  bf16x8 r;
  asm volatile("global_load_dwordx4 %0, %1, off sc0 sc1"
               : "=&v"(r) : "v"(p) : "memory");
  return r;
}
__device__ __forceinline__ bf16x8 sc_load16_wait(const void* p) {
  bf16x8 r;
  asm volatile("global_load_dwordx4 %0, %1, off sc0 sc1\n\ts_waitcnt vmcnt(0)"
               : "=&v"(r) : "v"(p) : "memory");
  return r;
}
__device__ __forceinline__ void sc_store_short(void* p, unsigned v) {
  asm volatile("global_store_short %0, %1, off sc0 sc1"
               :: "v"(p), "v"(v) : "memory");
}
__device__ __forceinline__ void sc_store_u32(void* p, unsigned v) {
  asm volatile("global_store_dword %0, %1, off sc0 sc1"
               :: "v"(p), "v"(v) : "memory");
}

// ---------------- init: zero flag region (1024 dwords) at the coherence point ----
__global__ void k_init(unsigned* __restrict__ flags) {
  for (int j = threadIdx.x; j < 1024; j += 256) sc_store_u32(flags + j, 0u);
}

// ---------------- drive GEMM: drive[m][n] = gain[n]*sum_f ext[m][f]*win[n][f] + bias[n]
__global__ __launch_bounds__(256) void k_gemm(const float* __restrict__ ext,
                                              const float* __restrict__ win,
                                              const float* __restrict__ gain,
                                              const float* __restrict__ bias,
                                              float* __restrict__ drive) {
  __shared__ float As[64][68];
  __shared__ float WsT[64][68];
  const int tid = threadIdx.x;
  const int m0 = blockIdx.y << 6;
  const int n0 = blockIdx.x << 6;
  const int tx = tid & 15, ty = tid >> 4;
  float acc[4][4] = {};
  for (int kc = 0; kc < FDIM; kc += 64) {
    __syncthreads();
#pragma unroll
    for (int rep = 0; rep < 4; ++rep) {
      int idx = tid + rep * 256;
      int row = idx >> 4;
      int c4 = (idx & 15) << 2;
      float4 av = *(const float4*)&ext[(size_t)(m0 + row) * FDIM + kc + c4];
      *(float4*)&As[row][c4] = av;
      float4 wv4 = *(const float4*)&win[(size_t)(n0 + row) * FDIM + kc + c4];
      WsT[c4 + 0][row] = wv4.x; WsT[c4 + 1][row] = wv4.y;
      WsT[c4 + 2][row] = wv4.z; WsT[c4 + 3][row] = wv4.w;
    }
    __syncthreads();
#pragma unroll 4
    for (int k = 0; k < 64; ++k) {
      float a_[4], w_[4];
#pragma unroll
      for (int i = 0; i < 4; ++i) a_[i] = As[ty * 4 + i][k];
#pragma unroll
      for (int j = 0; j < 4; ++j) w_[j] = WsT[k][tx * 4 + j];
#pragma unroll
      for (int i = 0; i < 4; ++i)
#pragma unroll
        for (int j = 0; j < 4; ++j) acc[i][j] = fmaf(a_[i], w_[j], acc[i][j]);
    }
  }
#pragma unroll
  for (int i = 0; i < 4; ++i) {
    int m = m0 + ty * 4 + i;
#pragma unroll
    for (int j = 0; j < 4; ++j) {
      int n = n0 + tx * 4 + j;
      drive[(size_t)m * NTOT + n] = gain[n] * acc[i][j] + bias[n];
    }
  }
}

// ---------------- weight prep: fragment-linear bf16 (B-operand) ----------------
__global__ __launch_bounds__(256) void k_wprep(const float* __restrict__ wv,
                                               unsigned short* __restrict__ wfrag) {
  const int sl = blockIdx.x;
  const int kk2 = blockIdx.y;
  const int tid = threadIdx.x;
  const int l = tid & 63, wt = tid >> 6;
  const int c = l & 15, g = l >> 4;
  const int i = wt * 16 + c;
  __align__(16) unsigned short tmp[8];
#pragma unroll
  for (int e = 0; e < 8; ++e) {
    int j = kk2 * 32 + g * 8 + e;
    tmp[e] = f2bf(wv[((size_t)sl * 64 + i) * 64 + j]);
  }
  size_t off = (((size_t)(sl * 2 + kk2) * 4 + wt) * 64 + l) * 8;
  *(uint4*)(wfrag + off) = *(const uint4*)tmp;
}

// ---- persistent recurrent kernel: R12 protocol (best measured: 5208 us) ----
__global__ __launch_bounds__(256, 1) void k_persist(const float* __restrict__ s0,
                                                    const int* __restrict__ rows_g,
                                                    const int* __restrict__ cols_g,
                                                    const unsigned short* __restrict__ wfrag,
                                                    char* __restrict__ sbuf,
                                                    float* __restrict__ out,
                                                    unsigned* __restrict__ flags) {
  __shared__ char sstage[MAXK * 2048];   // XOR-swizzled staged s col-blocks
  __shared__ int sh_cols[64];
  __shared__ int sh_lt, sh_eq;
  __shared__ unsigned m_pl, m_ph, m_cl, m_ch;

  const int r = blockIdx.x;
  const int tid = threadIdx.x;
  const int l = tid & 63, wt = tid >> 6;
  const int c = l & 15, g = l >> 4;
  const int n_own = r * 64 + wt * 16 + c;
  const float d_f = 0.81873077f;   // exp(-0.2f)
  const float omd = 1.0f - d_f;

  // ---- scan rows/cols: nnz range + producer/consumer masks ----
  if (tid == 0) { sh_lt = 0; sh_eq = 0; m_pl = 0; m_ph = 0; m_cl = 0; m_ch = 0; }
  __syncthreads();
  {
    int lt = 0, eq = 0;
    for (int k = tid; k < NNZ; k += 256) {
      int rv = rows_g[k], cv = cols_g[k];
      lt += (rv < r); eq += (rv == r);
      if (rv == r) { if (cv < 32) atomicOr(&m_pl, 1u << cv); else atomicOr(&m_ph, 1u << (cv - 32)); }
      if (cv == r) { if (rv < 32) atomicOr(&m_cl, 1u << rv); else atomicOr(&m_ch, 1u << (rv - 32)); }
    }
    atomicAdd(&sh_lt, lt); atomicAdd(&sh_eq, eq);
  }
  __syncthreads();
  const int start = sh_lt;
  const int cnt = min(sh_eq, 64);
  if (tid < cnt) sh_cols[tid] = cols_g[start + tid];
  __syncthreads();
  const unsigned long long pmask = ((unsigned long long)m_ph << 32) | m_pl;
  const unsigned long long cmask = ((unsigned long long)m_ch << 32) | m_cl;

  // ---- weights -> registers (guarded loads; proven layout from round 5/12) ----
  const char* wfb = (const char*)wfrag;
  bf16x8 wb0[MAXK], wb1[MAXK];
#pragma unroll
  for (int k = 0; k < MAXK; ++k) {
    if (k < cnt) {
      const char* bb = wfb + (size_t)(start + k) * 8192 + (size_t)(wt * 64 + l) * 16;
      wb0[k] = *(const bf16x8*)(bb);
      wb1[k] = *(const bf16x8*)(bb + 4096);
    }
  }
  const int cnt2 = min(cnt, MAXK);

  // ---- init state; publish s^(0) to ring slot 0 ----
  float sreg[4];
#pragma unroll
  for (int q = 0; q < 4; ++q) sreg[q] = s0[(size_t)(g * 4 + q) * NTOT + n_own];
  {
    char* me = sbuf + (size_t)r * 2048;
#pragma unroll
    for (int q = 0; q < 4; ++q)
      sc_store_short(me + (g * 4 + q) * 128 + (wt * 16 + c) * 2, (unsigned)f2bf(sreg[q]));
  }
  float drv[4];
#pragma unroll
  for (int q = 0; q < 4; ++q) drv[q] = out[(size_t)(g * 4 + q) * NTOT + n_own];

  asm volatile("s_waitcnt vmcnt(0)" ::: "memory");
  __syncthreads();
  if (tid == 0) sc_store_u32(&flags[(size_t)r * 16], 1u);

  const int raw0 = (c * 128 + g * 16) ^ ((c & 7) << 4);
  const int raw1 = (c * 128 + 64 + g * 16) ^ ((c & 7) << 4);
  const int nbytes = cnt2 * 2048;
  int budget = 1 << 20;   // global fast-fail budget: bug -> finish fast, never hang

  for (int t = 0; t < T_STEPS; ++t) {
    for (int ss = 0; ss < 5; ++ss) {
      const int i = t * 5 + ss + 1;

      // ---- poll (wave 0, participating lanes only): producers >= i; consumers >= i-6
      if (tid < 64) {
        const int nc = i - (DEPTH - 2);
        const bool par = (((pmask | cmask) >> l) & 1ull) != 0;
        const unsigned* fp = flags + (size_t)l * 16;   // one 64B line per WG
        for (;;) {
          unsigned f = 0x7FFFFFFFu;
          if (par)
            asm volatile("global_load_dword %0, %1, off sc0 sc1\n\ts_waitcnt vmcnt(0)"
                         : "=&v"(f) : "v"(fp) : "memory");
          unsigned long long bp = __ballot((int)f >= i);
          unsigned long long bc = __ballot((int)f >= nc);
          if (((bp & pmask) == pmask) && ((bc & cmask) == cmask)) break;
          if (--budget < 0) break;
          __builtin_amdgcn_s_sleep(1);
        }
      }
      __syncthreads();

      // ---- stage s col-blocks into swizzled LDS (pipelined coherent loads) ----
      const char* sb_prev = sbuf + (size_t)((i - 1) & (DEPTH - 1)) * SBUF_BYTES;
      bf16x8 stg[STG_SWEEPS];
#pragma unroll
      for (int sw = 0; sw < STG_SWEEPS; ++sw) {
        int off = tid * 16 + sw * 4096;
        if (off < nbytes) {
          int blk = off >> 11;
          int r2 = off & 2047;
          stg[sw] = sc_load16(sb_prev + (size_t)sh_cols[blk] * 2048 + r2);
        }
      }
      asm volatile("s_waitcnt vmcnt(0)" ::: "memory");
      __builtin_amdgcn_sched_barrier(0);
#pragma unroll
      for (int sw = 0; sw < STG_SWEEPS; ++sw) {
        int off = tid * 16 + sw * 4096;
        if (off < nbytes) {
          int blk = off >> 11;
          int r2 = off & 2047;
          int b = r2 >> 7;
          int jl = r2 & 127;
          *(bf16x8*)(sstage + blk * 2048 + ((b * 128 + jl) ^ ((b & 7) << 4))) = stg[sw];
        }
      }
      __syncthreads();

      // ---- block-sparse matvec: VGPR weights x LDS s-fragments ----
      f32x4 acc = {0.f, 0.f, 0.f, 0.f};
#pragma unroll
      for (int k = 0; k < MAXK; ++k) {
        if (k < cnt2) {
          const char* ab = sstage + k * 2048;
          bf16x8 a0 = *(const bf16x8*)(ab + raw0);
          bf16x8 a1 = *(const bf16x8*)(ab + raw1);
          acc = __builtin_amdgcn_mfma_f32_16x16x32_bf16(a0, wb0[k], acc, 0, 0, 0);
          acc = __builtin_amdgcn_mfma_f32_16x16x32_bf16(a1, wb1[k], acc, 0, 0, 0);
        }
      }
      for (int k = MAXK; k < cnt; ++k) {   // rare overflow: direct coherent reads
        const char* bb = wfb + (size_t)(start + k) * 8192 + (size_t)(wt * 64 + l) * 16;
        bf16x8 b0 = *(const bf16x8*)(bb);
        bf16x8 b1 = *(const bf16x8*)(bb + 4096);
        const char* ab = sb_prev + (size_t)sh_cols[k] * 2048 + c * 128 + g * 16;
        bf16x8 a0 = sc_load16_wait(ab);
        bf16x8 a1 = sc_load16_wait(ab + 64);
        acc = __builtin_amdgcn_mfma_f32_16x16x32_bf16(a0, b0, acc, 0, 0, 0);
        acc = __builtin_amdgcn_mfma_f32_16x16x32_bf16(a1, b1, acc, 0, 0, 0);
      }

      // ---- state update; publish s^(i); release flag BEFORE traj/prefetch ----
      char* me = sbuf + (size_t)(i & (DEPTH - 1)) * SBUF_BYTES + (size_t)r * 2048;
#pragma unroll
      for (int q = 0; q < 4; ++q) {
        float pre = acc[q] + drv[q];
        sreg[q] = d_f * sreg[q] + omd * tanhf(pre);
        sc_store_short(me + (g * 4 + q) * 128 + (wt * 16 + c) * 2, (unsigned)f2bf(sreg[q]));
      }
      asm volatile("s_waitcnt vmcnt(0)" ::: "memory");
      asm volatile("s_barrier" ::: "memory");
      if (tid == 0) sc_store_u32(&flags[(size_t)r * 16], (unsigned)(i + 1));

      if (ss == 4) {
        // traj[t] = s (plain cached stores, drained lazily by later vmcnts)
#pragma unroll
        for (int q = 0; q < 4; ++q)
          out[((size_t)t * BATCH + (g * 4 + q)) * NTOT + n_own] = sreg[q];
        if (t + 1 < T_STEPS) {
#pragma unroll
          for (int q = 0; q < 4; ++q)
            drv[q] = out[((size_t)(t + 1) * BATCH + (g * 4 + q)) * NTOT + n_own];
        }
      }
    }
  }
}

// ---------------- launcher ----------------
extern "C" void kernel_launch(void* const* d_in, const int* in_sizes, int n_in,
                              void* d_out, int out_size, void* d_ws, size_t ws_size,
                              hipStream_t stream) {
  const float* ext  = (const float*)d_in[0];
  const float* win  = (const float*)d_in[1];
  const float* gain = (const float*)d_in[2];
  const float* bias = (const float*)d_in[3];
  const float* wv   = (const float*)d_in[4];
  const float* s0   = (const float*)d_in[5];
  const int* rows = (const int*)d_in[8];
  const int* cols = (const int*)d_in[9];
  float* out = (float*)d_out;

  char* ws = (char*)d_ws;
  unsigned* flags = (unsigned*)(ws + FLAGS_OFF);
  char* sbuf = ws + SBF_OFF;
  unsigned short* wfrag = (unsigned short*)(ws + WFRAG_OFF);

  k_init<<<1, 256, 0, stream>>>(flags);
  k_gemm<<<dim3(64, 64), 256, 0, stream>>>(ext, win, gain, bias, out);
  k_wprep<<<dim3(512, 2), 256, 0, stream>>>(wv, wfrag);
  k_persist<<<NWG, 256, 0, stream>>>(s0, rows, cols, wfrag, sbuf, out, flags);
}